// Round 15
// baseline (102.419 us; speedup 1.0000x reference)
//
#include <hip/hip_runtime.h>
#include <math.h>

#define NSTEP  730
#define NGRID  1500
#define LENF   15
#define PRECS  1e-5f
#define CH     16
#define NCHUNK 46                  // 45 full chunks + tail of 10
#define QROW   260                 // 64 float4 = 256 dw + 4 pad
#define OTW    21                  // out-tile row: 20 + 1 pad

// flag indices
#define F_XPROD 0
#define F_XCA   1
#define F_XCB   2
#define F_RTP   3
#define F_RTC   4
#define F_SP    5
#define F_SC    6
#define F_QP    7
#define F_QC    8

static __device__ __forceinline__ float fast_pow01(float x, float y) {
    return __builtin_amdgcn_exp2f(y * __builtin_amdgcn_logf(x));
}
static __device__ __forceinline__ void wait_ge(volatile int* f, int v) {
    if (v <= 0) return;
    while (*f < v) __builtin_amdgcn_s_sleep(1);
    asm volatile("" ::: "memory");
}
static __device__ __forceinline__ void publish(volatile int* f, int v, bool leader) {
    asm volatile("s_waitcnt lgkmcnt(0)" ::: "memory");   // data visible first
    if (leader) *f = v;
}

// Block = 256 threads = 4 waves = self-timed 4-stage pipeline over 4 grids,
// 375 blocks. Stages communicate via SPSC flag-guarded LDS rings (depth 2-3):
//   W0 snow(c) -> rtbuf;  W1 soil(c) (pow chain) -> soilbuf;
//   W2 resp(c) -> qbuf;   W3: x staging (2 ahead) + mu-reduce/conv/store.
// No __syncthreads in steady state: waves decouple, slack absorbed by rings.
__global__ __launch_bounds__(256, 1)
void hbv_scan_kernel(const float* __restrict__ x,       // (730,1500,3)
                     const float* __restrict__ params,  // (1500,12,16)
                     const float* __restrict__ rtwts,   // (1500,2)
                     float* __restrict__ out)           // (730,1500,5)
{
    __shared__ float  xring[3*CH*16];    //  3.0 KB (slot c%3)
    __shared__ float  rtbuf[2*CH*64];    //  8.0 KB
    __shared__ float2 soilbuf[2*CH*64];  // 16.0 KB (re, ETact)
    __shared__ float  qbuf[2*CH*QROW];   // 32.5 KB
    __shared__ float  outtile[CH*OTW];   //  1.3 KB
    __shared__ float  ring[4*64];        //  1.0 KB
    __shared__ int    flags[16];         //  64 B    (total ~62 KB)

    const int tid  = threadIdx.x;
    const int wid  = tid >> 6;
    const int lane = tid & 63;
    const int gl = lane >> 4, m = lane & 15;
    const int b  = blockIdx.x;
    const int g  = b*4 + gl;
    const bool leader = (lane == 0);
    const float inv16 = 1.f/16.f;
    volatile int* fl = flags;

    if (tid < 16) flags[tid] = 0;
    ring[tid] = 0.f;                     // 256 floats, one per thread
    __syncthreads();                     // the only block-wide barrier

    if (wid == 0) {
        // ================= W0: snow recursion =================
        const float pTT     = -2.5f + params[(g*12+8)*16+m]*5.f;
        const float pCFMAX  =  0.5f + params[(g*12+9)*16+m]*9.5f;
        const float pCFR    =          params[(g*12+10)*16+m]*0.1f;
        const float pCWH    =          params[(g*12+11)*16+m]*0.2f;
        const float refCoef = pCFR*pCFMAX;
        const float negCMTT = -pCFMAX*pTT;
        const float refCTT  = refCoef*pTT;
        float SP = 0.001f, MW = 0.001f;
        for (int c = 0; c < NCHUNK; ++c) {
            wait_ge(&fl[F_XPROD], c+1);
            wait_ge(&fl[F_RTC],   c-1);
            const float* xb = &xring[(c%3)*CH*16 + gl*4];
            float* rb = &rtbuf[(c&1)*CH*64 + lane];
            #pragma unroll
            for (int s = 0; s < CH; ++s) {
                const float2 PT = *(const float2*)(xb + s*16);
                const float Pm = PT.x, Tm = PT.y;
                const float RAIN    = (Tm >= pTT) ? Pm : 0.f;
                const float SNOW    = Pm - RAIN;
                const float meltcap = fmaxf(fmaf(pCFMAX, Tm, negCMTT), 0.f);
                const float refcap  = fmaxf(fmaf(-refCoef, Tm, refCTT), 0.f);
                const float SP1 = SP + SNOW;
                const float melt = fminf(meltcap, SP1);
                const float MW1 = MW + melt;
                const float refreeze = fminf(refcap, MW1);
                SP = SP1 - melt + refreeze;
                const float MW2 = MW1 - refreeze;
                const float tosoil = fmaxf(fmaf(-pCWH, SP, MW2), 0.f);
                MW = MW2 - tosoil;
                rb[s*64] = RAIN + tosoil;
            }
            publish(&fl[F_RTP], c+1, leader);
            publish(&fl[F_XCA], c+1, leader);
        }
    } else if (wid == 1) {
        // ================= W1: soil (SM/pow) recursion =================
        const float pBETA = 1.f  + params[(g*12+0)*16+m]*5.f;
        const float pFC   = 50.f + params[(g*12+1)*16+m]*950.f;
        const float pLP   = 0.2f + params[(g*12+5)*16+m]*0.8f;
        const float invFC = 1.f/pFC, invLPFC = 1.f/(pLP*pFC);
        float SM = 0.001f;
        for (int c = 0; c < NCHUNK; ++c) {
            wait_ge(&fl[F_RTP], c+1);          // implies x(c) staged too
            wait_ge(&fl[F_SC],  c-1);
            const float* xe = &xring[(c%3)*CH*16 + gl*4 + 2];
            const float* rb = &rtbuf[(c&1)*CH*64 + lane];
            float2* sb = &soilbuf[(c&1)*CH*64 + lane];
            #pragma unroll
            for (int s = 0; s < CH; ++s) {
                const float rt = rb[s*64];
                const float Em = xe[s*16];
                const float cE = Em * invLPFC;               // off-chain
                const float SMprt = SM + rt;                 // off critical tail
                const float sw = fast_pow01(SM*invFC, pBETA);// <=1 by invariant
                const float SM1 = fmaf(-rt, sw, SMprt);
                const float SM2 = fminf(SM1, pFC);
                const float ETact = fminf(fminf(SM2*cE, SM2), Em);  // v_min3
                const float re = fmaf(rt, sw, SM1 - SM2);    // recharge+excess
                SM = fmaxf(SM2 - ETact, PRECS);
                sb[s*64] = make_float2(re, ETact);
            }
            publish(&fl[F_SP],  c+1, leader);
            publish(&fl[F_XCB], c+1, leader);
            publish(&fl[F_RTC], c+1, leader);
        }
    } else if (wid == 2) {
        // ================= W2: response (SUZ,SLZ) recursion =================
        const float pK0   = 0.05f  + params[(g*12+2)*16+m]*0.85f;
        const float pK1   = 0.01f  + params[(g*12+3)*16+m]*0.49f;
        const float pK2   = 0.001f + params[(g*12+4)*16+m]*0.199f;
        const float pPERC =          params[(g*12+6)*16+m]*10.f;
        const float pUZL  =          params[(g*12+7)*16+m]*100.f;
        const float oneMinusK0 = 1.f - pK0, K0UZL = pK0*pUZL;
        float SUZ = 0.001f, SLZ = 0.001f;
        for (int c = 0; c < NCHUNK; ++c) {
            wait_ge(&fl[F_SP], c+1);
            wait_ge(&fl[F_QC], c-1);
            const float2* sb = &soilbuf[(c&1)*CH*64 + lane];
            float* qb = &qbuf[(c&1)*CH*QROW + lane*4];
            #pragma unroll
            for (int s = 0; s < CH; ++s) {
                const float2 rE = sb[s*64];
                const float SUZ1 = SUZ + rE.x;
                const float SUZ2 = fmaxf(SUZ1 - pPERC, 0.f);
                const float PERC = SUZ1 - SUZ2;
                const float SUZ3 = fminf(SUZ2, fmaf(SUZ2, oneMinusK0, K0UZL));
                const float Q0 = SUZ2 - SUZ3;
                const float Q1 = pK1 * SUZ3;
                SUZ = SUZ3 - Q1;
                const float SLZ1 = SLZ + PERC;
                const float Q2 = pK2 * SLZ1;
                SLZ = SLZ1 - Q2;
                *(float4*)(qb + s*QROW) = make_float4(Q0, Q1, Q2, rE.y);
            }
            publish(&fl[F_QP], c+1, leader);
            publish(&fl[F_SC], c+1, leader);
        }
    } else {
        // ================= W3: x staging (2 ahead) + epilogue =================
        float wq[LENF];
        {
            const float ta  = rtwts[g*2+0] * 2.9f;
            const float tbv = rtwts[g*2+1] * 6.5f;
            const float aa = fmaxf(ta, 0.f) + 0.1f;
            const float th = fmaxf(tbv, 0.f) + 0.5f;
            const float c0v = expf(-lgammaf(aa)) * powf(th, -aa);
            float wsum = 0.f;
            #pragma unroll
            for (int k = 0; k < LENF; ++k) {
                const float tt = (float)k + 0.5f;
                wq[k] = c0v * powf(tt, aa-1.f) * expf(-tt/th);
                wsum += wq[k];
            }
            const float ws = inv16 / wsum;
            #pragma unroll
            for (int k = 0; k < LENF; ++k) wq[k] *= ws;
        }
        int rbase[3], bcol[3], lslot[3];
        #pragma unroll
        for (int j = 0; j < 3; ++j) {
            const int idx = lane + 64*j;
            const int r = idx/12, rem = idx - 12*r;
            const int gi = rem/3, ch = rem - 3*gi;
            rbase[j] = r;
            bcol[j]  = b*12 + gi*3 + ch;
            lslot[j] = r*16 + gi*4 + ch;
        }
        int st_o[5], st_g[5];
        #pragma unroll
        for (int j = 0; j < 5; ++j) {
            const int idx = lane + 64*j;
            const int tt = idx/20, cl = idx - 20*tt;
            st_o[j] = tt*OTW + cl;
            st_g[j] = tt*7500 + cl;
        }

        float stg[3];
        // prime: load+commit chunk 0, then issue loads for chunk 1
        #pragma unroll
        for (int j = 0; j < 3; ++j) stg[j] = x[rbase[j]*4500 + bcol[j]];
        asm volatile("s_waitcnt vmcnt(0)" ::: "memory");
        {
            float* xd = &xring[0];
            xd[lslot[0]] = stg[0]; xd[lslot[1]] = stg[1]; xd[lslot[2]] = stg[2];
        }
        publish(&fl[F_XPROD], 1, leader);
        #pragma unroll
        for (int j = 0; j < 3; ++j) {
            int rr = CH + rbase[j]; rr = (rr < NSTEP) ? rr : (NSTEP-1);
            stg[j] = x[rr*4500 + bcol[j]];
        }

        for (int q = 0; q < NCHUNK; ++q) {
            // 1. commit x(q+1) (loaded last iteration) — not gated on epilogue
            if (q+1 < NCHUNK) {
                asm volatile("s_waitcnt vmcnt(0)" ::: "memory");
                float* xd = &xring[((q+1)%3)*CH*16];
                xd[lslot[0]] = stg[0]; xd[lslot[1]] = stg[1]; xd[lslot[2]] = stg[2];
                publish(&fl[F_XPROD], q+2, leader);
            }
            // 2. issue loads for chunk q+2 (ring depth 3: need cons >= q)
            if (q+2 < NCHUNK) {
                wait_ge(&fl[F_XCA], q);
                wait_ge(&fl[F_XCB], q);
                #pragma unroll
                for (int j = 0; j < 3; ++j) {
                    int rr = (q+2)*CH + rbase[j];
                    rr = (rr < NSTEP) ? rr : (NSTEP-1);
                    stg[j] = x[rr*4500 + bcol[j]];
                }
            }
            // 3. epilogue for chunk q
            wait_ge(&fl[F_QP], q+1);
            {
                const int nstep = (q == NCHUNK-1) ? (NSTEP - (NCHUNK-1)*CH) : CH;
                const float* qb = &qbuf[(q&1)*CH*QROW];
                const int t = q*CH + m;
                float a0=0.f, a1=0.f, a2=0.f, a3=0.f;
                if (m < nstep) {
                    #pragma unroll
                    for (int i = 0; i < 16; ++i) {
                        const float4 v = *(const float4*)&qb[m*QROW + gl*64 + i*4];
                        a0 += v.x; a1 += v.y; a2 += v.z; a3 += v.w;
                    }
                    ring[gl*64 + (t & 63)] = a0 + a1 + a2;
                }
                asm volatile("s_waitcnt lgkmcnt(0)" ::: "memory");
                if (m < nstep) {
                    float acc = 0.f;
                    #pragma unroll
                    for (int k = 0; k < LENF; ++k)
                        acc += wq[k] * ring[gl*64 + ((t - k) & 63)];
                    float* ot = &outtile[m*OTW + gl*5];
                    ot[0] = acc;
                    ot[1] = a0*inv16; ot[2] = a1*inv16;
                    ot[3] = a2*inv16; ot[4] = a3*inv16;
                }
                asm volatile("s_waitcnt lgkmcnt(0)" ::: "memory");
                const int ndw = nstep*20;
                float* ob = out + q*CH*7500 + b*20;
                #pragma unroll
                for (int j = 0; j < 5; ++j) {
                    const int idx = lane + 64*j;
                    if (idx < ndw) ob[st_g[j]] = outtile[st_o[j]];
                }
            }
            publish(&fl[F_QC], q+1, leader);
        }
    }
}

extern "C" void kernel_launch(void* const* d_in, const int* in_sizes, int n_in,
                              void* d_out, int out_size, void* d_ws, size_t ws_size,
                              hipStream_t stream)
{
    const float* x      = (const float*)d_in[0];
    const float* params = (const float*)d_in[1];
    const float* rt     = (const float*)d_in[2];
    float* out = (float*)d_out;

    dim3 grid(NGRID / 4), block(256);
    hipLaunchKernelGGL(hbv_scan_kernel, grid, block, 0, stream, x, params, rt, out);
}

// Round 16
// 91.185 us; speedup vs baseline: 1.1232x; 1.1232x over previous
//
#include <hip/hip_runtime.h>
#include <math.h>

#define NSTEP  730
#define NGRID  1500
#define LENF   15
#define PRECS  1e-5f
#define CH     16
#define NCHUNK 46                  // 45 full chunks + tail of 10
#define NPHASE (NCHUNK+3)          // 4-stage pipeline fill/drain
#define XROWDW 32                  // LDS x row: 8 grids * 4 dw
#define QROW   524                 // A rows at 0, B rows at +264; 16B-aligned
#define BOFF   264
#define OTW    41                  // out-tile row: 40 + 1 pad

static __device__ __forceinline__ float fexp2(float v){ return __builtin_amdgcn_exp2f(v); }
static __device__ __forceinline__ float flog2(float v){ return __builtin_amdgcn_logf(v); }

// Block = 256 threads = 4 waves = 4 pipeline stages over 8 grids (two
// interleaved chain-sets A/B per stage wave), 188 blocks -> at most ONE block
// per CU (fixes R14's 2-block straggler CUs; halves barriers per grid).
//   W0 snow(c):   dual (SP,MW) recursions -> rt pairs
//   W1 soil(c-1): dual SM recursions (exp2/log2 chain, max3 form) -> (re,ET)
//   W2 resp(c-2): dual (SUZ,SLZ) recursions -> q-vectors
//   W3 epi(c-3):  2 mu-reduces/lane + ring conv + coalesced store; stages x
__global__ __launch_bounds__(256, 1)
void hbv_scan_kernel(const float* __restrict__ x,       // (730,1500,3)
                     const float* __restrict__ params,  // (1500,12,16)
                     const float* __restrict__ rtwts,   // (1500,2)
                     float* __restrict__ out)           // (730,1500,5)
{
    __shared__ float  xring[3*CH*XROWDW];   //  6.0 KB (slot c%3)
    __shared__ float2 rtbuf[2*CH*64];       // 16.0 KB ({rtA, rtB})
    __shared__ float4 soilbuf[2*CH*64];     // 32.0 KB ({reA,etA,reB,etB})
    __shared__ float  qbuf[2*CH*QROW];      // 67.1 KB
    __shared__ float  outtile[CH*OTW];      //  2.6 KB
    __shared__ float  ring[8*64];           //  2.0 KB   (total ~126 KB)

    const int tid  = threadIdx.x;
    const int wid  = tid >> 6;
    const int lane = tid & 63;
    const int gl = lane >> 4, m = lane & 15;
    const int b  = blockIdx.x;
    const int gA = b*8 + gl;                      // ≤ 1499 always
    const int gB = gA + 4;                        // 1500..1503 phantom for b=187
    const int gBc = (gB < NGRID) ? gB : (NGRID-1);
    const float inv16 = 1.f/16.f;

    if (wid == 0) {
        // ================= W0: dual snow recursions =================
        const float TTa = -2.5f + params[(gA*12+8)*16+m]*5.f;
        const float CMa =  0.5f + params[(gA*12+9)*16+m]*9.5f;
        const float RCa = (params[(gA*12+10)*16+m]*0.1f)*CMa;
        const float WHa =  params[(gA*12+11)*16+m]*0.2f;
        const float nCMTTa = -CMa*TTa, rCTTa = RCa*TTa;
        const float TTb = -2.5f + params[(gBc*12+8)*16+m]*5.f;
        const float CMb =  0.5f + params[(gBc*12+9)*16+m]*9.5f;
        const float RCb = (params[(gBc*12+10)*16+m]*0.1f)*CMb;
        const float WHb =  params[(gBc*12+11)*16+m]*0.2f;
        const float nCMTTb = -CMb*TTb, rCTTb = RCb*TTb;
        float SPa=0.001f, MWa=0.001f, SPb=0.001f, MWb=0.001f;
        __syncthreads();
        for (int p = 0; p < NPHASE; ++p) {
            if (p < NCHUNK) {
                const float* xb = &xring[(p%3)*CH*XROWDW];
                float2* rb = &rtbuf[(p&1)*CH*64 + lane];
                #pragma unroll
                for (int s = 0; s < CH; ++s) {
                    const float2 PTa = *(const float2*)(xb + s*XROWDW + gl*4);
                    const float2 PTb = *(const float2*)(xb + s*XROWDW + 16 + gl*4);
                    float rtA, rtB;
                    {   const float Pm = PTa.x, Tm = PTa.y;
                        const float RAIN = (Tm >= TTa) ? Pm : 0.f;
                        const float mc = fmaxf(fmaf(CMa, Tm, nCMTTa), 0.f);
                        const float rc = fmaxf(fmaf(-RCa, Tm, rCTTa), 0.f);
                        const float SP1 = SPa + (Pm - RAIN);
                        const float melt = fminf(mc, SP1);
                        const float MW1 = MWa + melt;
                        const float rf = fminf(rc, MW1);
                        SPa = SP1 - melt + rf;
                        const float MW2 = MW1 - rf;
                        const float ts = fmaxf(fmaf(-WHa, SPa, MW2), 0.f);
                        MWa = MW2 - ts;
                        rtA = RAIN + ts; }
                    {   const float Pm = PTb.x, Tm = PTb.y;
                        const float RAIN = (Tm >= TTb) ? Pm : 0.f;
                        const float mc = fmaxf(fmaf(CMb, Tm, nCMTTb), 0.f);
                        const float rc = fmaxf(fmaf(-RCb, Tm, rCTTb), 0.f);
                        const float SP1 = SPb + (Pm - RAIN);
                        const float melt = fminf(mc, SP1);
                        const float MW1 = MWb + melt;
                        const float rf = fminf(rc, MW1);
                        SPb = SP1 - melt + rf;
                        const float MW2 = MW1 - rf;
                        const float ts = fmaxf(fmaf(-WHb, SPb, MW2), 0.f);
                        MWb = MW2 - ts;
                        rtB = RAIN + ts; }
                    rb[s*64] = make_float2(rtA, rtB);
                }
            }
            __syncthreads();
        }
    } else if (wid == 1) {
        // ================= W1: dual soil (SM) recursions =================
        const float bA = 1.f + params[(gA*12+0)*16+m]*5.f;
        const float FCa = 50.f + params[(gA*12+1)*16+m]*950.f;
        const float LPa = 0.2f + params[(gA*12+5)*16+m]*0.8f;
        const float iLPFCa = 1.f/(LPa*FCa);
        const float cA = -bA * flog2(FCa);        // sw = exp2(bA*log2(SM)+cA)
        const float bB = 1.f + params[(gBc*12+0)*16+m]*5.f;
        const float FCb = 50.f + params[(gBc*12+1)*16+m]*950.f;
        const float LPb = 0.2f + params[(gBc*12+5)*16+m]*0.8f;
        const float iLPFCb = 1.f/(LPb*FCb);
        const float cB = -bB * flog2(FCb);
        float SMa = 0.001f, SMb = 0.001f;
        __syncthreads();
        for (int p = 0; p < NPHASE; ++p) {
            if (p >= 1 && p-1 < NCHUNK) {
                const int c = p-1;
                const float* xe = &xring[(c%3)*CH*XROWDW];
                const float2* rb = &rtbuf[(c&1)*CH*64 + lane];
                float4* sb = &soilbuf[(c&1)*CH*64 + lane];
                #pragma unroll
                for (int s = 0; s < CH; ++s) {
                    const float2 rt2 = rb[s*64];
                    const float EmA = xe[s*XROWDW + gl*4 + 2];
                    const float EmB = xe[s*XROWDW + 16 + gl*4 + 2];
                    float reA, etA, reB, etB;
                    {   const float sw = fexp2(fmaf(bA, flog2(SMa), cA));
                        const float SM1 = fmaf(-rt2.x, sw, SMa + rt2.x);
                        const float SM2 = fminf(SM1, FCa);
                        const float cE = EmA * iLPFCa;
                        etA = fminf(fminf(SM2*cE, SM2), EmA);          // v_min3
                        reA = fmaf(rt2.x, sw, SM1 - SM2);
                        SMa = fmaxf(fmaxf(fmaf(-SM2, cE, SM2), SM2 - EmA), PRECS); }
                    {   const float sw = fexp2(fmaf(bB, flog2(SMb), cB));
                        const float SM1 = fmaf(-rt2.y, sw, SMb + rt2.y);
                        const float SM2 = fminf(SM1, FCb);
                        const float cE = EmB * iLPFCb;
                        etB = fminf(fminf(SM2*cE, SM2), EmB);
                        reB = fmaf(rt2.y, sw, SM1 - SM2);
                        SMb = fmaxf(fmaxf(fmaf(-SM2, cE, SM2), SM2 - EmB), PRECS); }
                    sb[s*64] = make_float4(reA, etA, reB, etB);
                }
            }
            __syncthreads();
        }
    } else if (wid == 2) {
        // ================= W2: dual response recursions =================
        const float K0a = 0.05f  + params[(gA*12+2)*16+m]*0.85f;
        const float K1a = 0.01f  + params[(gA*12+3)*16+m]*0.49f;
        const float K2a = 0.001f + params[(gA*12+4)*16+m]*0.199f;
        const float PCa =          params[(gA*12+6)*16+m]*10.f;
        const float ULa =          params[(gA*12+7)*16+m]*100.f;
        const float oK0a = 1.f - K0a, KUa = K0a*ULa;
        const float K0b = 0.05f  + params[(gBc*12+2)*16+m]*0.85f;
        const float K1b = 0.01f  + params[(gBc*12+3)*16+m]*0.49f;
        const float K2b = 0.001f + params[(gBc*12+4)*16+m]*0.199f;
        const float PCb =          params[(gBc*12+6)*16+m]*10.f;
        const float ULb =          params[(gBc*12+7)*16+m]*100.f;
        const float oK0b = 1.f - K0b, KUb = K0b*ULb;
        float SUZa=0.001f, SLZa=0.001f, SUZb=0.001f, SLZb=0.001f;
        __syncthreads();
        for (int p = 0; p < NPHASE; ++p) {
            if (p >= 2 && p-2 < NCHUNK) {
                const int c = p-2;
                const float4* sb = &soilbuf[(c&1)*CH*64 + lane];
                float* qb = &qbuf[(c&1)*CH*QROW];
                #pragma unroll
                for (int s = 0; s < CH; ++s) {
                    const float4 se = sb[s*64];
                    {   const float SUZ1 = SUZa + se.x;
                        const float SUZ2 = fmaxf(SUZ1 - PCa, 0.f);
                        const float PERC = SUZ1 - SUZ2;
                        const float SUZ3 = fminf(SUZ2, fmaf(SUZ2, oK0a, KUa));
                        const float Q0 = SUZ2 - SUZ3;
                        const float Q1 = K1a * SUZ3;
                        SUZa = SUZ3 - Q1;
                        const float SLZ1 = SLZa + PERC;
                        const float Q2 = K2a * SLZ1;
                        SLZa = SLZ1 - Q2;
                        *(float4*)&qbuf[(c&1)*CH*QROW + s*QROW + lane*4]
                            = make_float4(Q0, Q1, Q2, se.y); }
                    {   const float SUZ1 = SUZb + se.z;
                        const float SUZ2 = fmaxf(SUZ1 - PCb, 0.f);
                        const float PERC = SUZ1 - SUZ2;
                        const float SUZ3 = fminf(SUZ2, fmaf(SUZ2, oK0b, KUb));
                        const float Q0 = SUZ2 - SUZ3;
                        const float Q1 = K1b * SUZ3;
                        SUZb = SUZ3 - Q1;
                        const float SLZ1 = SLZb + PERC;
                        const float Q2 = K2b * SLZ1;
                        SLZb = SLZ1 - Q2;
                        *(float4*)&qb[s*QROW + BOFF + lane*4]
                            = make_float4(Q0, Q1, Q2, se.w); }
                }
            }
            __syncthreads();
        }
    } else {
        // ================= W3: epilogue (A and B) + x staging =================
        float wqA[LENF], wqB[LENF];
        {
            auto mkw = [&](int g, float* wq) {
                const float ta  = rtwts[g*2+0] * 2.9f;
                const float tbv = rtwts[g*2+1] * 6.5f;
                const float aa = fmaxf(ta, 0.f) + 0.1f;
                const float th = fmaxf(tbv, 0.f) + 0.5f;
                const float c0v = expf(-lgammaf(aa)) * powf(th, -aa);
                float wsum = 0.f;
                #pragma unroll
                for (int k = 0; k < LENF; ++k) {
                    const float tt = (float)k + 0.5f;
                    wq[k] = c0v * powf(tt, aa-1.f) * expf(-tt/th);
                    wsum += wq[k];
                }
                const float ws = inv16 / wsum;
                #pragma unroll
                for (int k = 0; k < LENF; ++k) wq[k] *= ws;
            };
            mkw(gA, wqA);
            mkw(gBc, wqB);
        }
        int rbase[6], gcol[6], lslot[6];
        #pragma unroll
        for (int j = 0; j < 6; ++j) {
            const int idx = lane + 64*j;
            const int r = idx/24, rem = idx - 24*r;
            const int g8 = rem/3, ch = rem - 3*g8;
            rbase[j] = r;
            const int gc = b*24 + g8*3 + ch;
            gcol[j] = (gc < 4500) ? gc : (4497 + ch);
            lslot[j] = r*XROWDW + g8*4 + ch;
        }
        int st_o[10], st_g[10], st_ok[10];
        #pragma unroll
        for (int j = 0; j < 10; ++j) {
            const int idx = lane + 64*j;
            const int tt = idx/40, cl = idx - 40*tt;
            st_o[j] = tt*OTW + cl;
            st_g[j] = tt*7500 + cl;
            st_ok[j] = (b*40 + cl < 7500);
        }
        #pragma unroll
        for (int i = 0; i < 8; ++i) ring[lane + 64*i] = 0.f;
        float stg[6];
        #pragma unroll
        for (int j = 0; j < 6; ++j) stg[j] = x[rbase[j]*4500 + gcol[j]];
        #pragma unroll
        for (int j = 0; j < 6; ++j) xring[lslot[j]] = stg[j];   // chunk 0
        __syncthreads();

        for (int p = 0; p < NPHASE; ++p) {
            const bool ld = (p+1 < NCHUNK);
            if (ld) {
                #pragma unroll
                for (int j = 0; j < 6; ++j) {
                    int rr = (p+1)*CH + rbase[j];
                    rr = (rr < NSTEP) ? rr : (NSTEP-1);
                    stg[j] = x[rr*4500 + gcol[j]];
                }
            }
            const int q = p - 3;
            if (q >= 0) {
                const int nstep = (q == NCHUNK-1) ? (NSTEP - (NCHUNK-1)*CH) : CH;
                const float* qb = &qbuf[(q&1)*CH*QROW];
                const int t = q*CH + m;
                float a0=0,a1=0,a2=0,a3=0, e0=0,e1=0,e2=0,e3=0;
                if (m < nstep) {
                    #pragma unroll
                    for (int i = 0; i < 16; ++i) {
                        const float4 v = *(const float4*)&qb[m*QROW + gl*64 + i*4];
                        a0 += v.x; a1 += v.y; a2 += v.z; a3 += v.w;
                    }
                    #pragma unroll
                    for (int i = 0; i < 16; ++i) {
                        const float4 v = *(const float4*)&qb[m*QROW + BOFF + gl*64 + i*4];
                        e0 += v.x; e1 += v.y; e2 += v.z; e3 += v.w;
                    }
                    ring[gl*64 + (t & 63)]     = a0 + a1 + a2;
                    ring[(4+gl)*64 + (t & 63)] = e0 + e1 + e2;
                }
                asm volatile("s_waitcnt lgkmcnt(0)" ::: "memory");
                if (m < nstep) {
                    float accA = 0.f, accB = 0.f;
                    #pragma unroll
                    for (int k = 0; k < LENF; ++k) {
                        accA += wqA[k] * ring[gl*64 + ((t - k) & 63)];
                        accB += wqB[k] * ring[(4+gl)*64 + ((t - k) & 63)];
                    }
                    float* otA = &outtile[m*OTW + gl*5];
                    otA[0]=accA; otA[1]=a0*inv16; otA[2]=a1*inv16;
                    otA[3]=a2*inv16; otA[4]=a3*inv16;
                    float* otB = &outtile[m*OTW + 20 + gl*5];
                    otB[0]=accB; otB[1]=e0*inv16; otB[2]=e1*inv16;
                    otB[3]=e2*inv16; otB[4]=e3*inv16;
                }
                asm volatile("s_waitcnt lgkmcnt(0)" ::: "memory");
                const int ndw = nstep*40;
                float* ob = out + q*CH*7500 + b*40;
                #pragma unroll
                for (int j = 0; j < 10; ++j) {
                    const int idx = lane + 64*j;
                    if (idx < ndw && st_ok[j]) ob[st_g[j]] = outtile[st_o[j]];
                }
            }
            if (ld) {
                float* xd = &xring[((p+1)%3)*CH*XROWDW];
                #pragma unroll
                for (int j = 0; j < 6; ++j) xd[lslot[j]] = stg[j];
            }
            __syncthreads();
        }
    }
}

extern "C" void kernel_launch(void* const* d_in, const int* in_sizes, int n_in,
                              void* d_out, int out_size, void* d_ws, size_t ws_size,
                              hipStream_t stream)
{
    const float* x      = (const float*)d_in[0];
    const float* params = (const float*)d_in[1];
    const float* rt     = (const float*)d_in[2];
    float* out = (float*)d_out;

    dim3 grid(188), block(256);   // ceil(1500/8) blocks, <=1 block per CU
    hipLaunchKernelGGL(hbv_scan_kernel, grid, block, 0, stream, x, params, rt, out);
}

// Round 17
// 61.662 us; speedup vs baseline: 1.6610x; 1.4788x over previous
//
#include <hip/hip_runtime.h>
#include <math.h>

#define NSTEP  730
#define NGRID  1500
#define LENF   15
#define PRECS  1e-5f
#define CH     16
#define NCHUNK 46                  // 45 full chunks + tail of 10
#define NPHASE (NCHUNK+3)          // 4-stage pipeline fill/drain
#define QROW   260                 // 64 float4 = 256 dw + 4 pad
#define OTW    21                  // out-tile row: 20 + 1 pad

static __device__ __forceinline__ float fexp2(float v){ return __builtin_amdgcn_exp2f(v); }
static __device__ __forceinline__ float flog2(float v){ return __builtin_amdgcn_logf(v); }

// Block = 256 threads = 4 waves = 4 pipeline stages over 4 grids, 375 blocks
// (R14 structure — best so far). NEW: every stage BURSTS its phase's LDS
// reads into registers up front (one lgkm drain), then runs the 16-step
// chain register-only. Theory: compiler's just-before-use LDS scheduling
// exposed ~120cyc ds_read latency per STEP (~1900 cyc/phase, the measured
// overhead); bursting pays it once per PHASE.
//   W0 snow(c):   (SP,MW) rec -> rt      W1 soil(c-1): SM rec (exp2 chain)
//   W2 resp(c-2): (SUZ,SLZ) rec -> q     W3 epi(c-3):  reduce+conv+store, x-stage
__global__ __launch_bounds__(256, 1)
void hbv_scan_kernel(const float* __restrict__ x,       // (730,1500,3)
                     const float* __restrict__ params,  // (1500,12,16)
                     const float* __restrict__ rtwts,   // (1500,2)
                     float* __restrict__ out)           // (730,1500,5)
{
    __shared__ float  xring[3*CH*16];    //  3.0 KB (slot c%3)
    __shared__ float  rtbuf[2*CH*64];    //  8.0 KB
    __shared__ float2 soilbuf[2*CH*64];  // 16.0 KB (re, ETact)
    __shared__ float  qbuf[2*CH*QROW];   // 32.5 KB
    __shared__ float  outtile[CH*OTW];   //  1.3 KB
    __shared__ float  ring[4*64];        //  1.0 KB  (total ~62 KB, 2 blocks/CU)

    const int tid  = threadIdx.x;
    const int wid  = tid >> 6;
    const int lane = tid & 63;
    const int gl = lane >> 4, m = lane & 15;
    const int b  = blockIdx.x;
    const int g  = b*4 + gl;
    const float inv16 = 1.f/16.f;

    // prestage chunk 0 (W3) + zero conv ring, one uniform barrier
    if (wid == 3) {
        #pragma unroll
        for (int j = 0; j < 3; ++j) {
            const int idx = lane + 64*j;
            const int r = idx/12, rem = idx - 12*r;
            const int gi = rem/3, ch = rem - 3*gi;
            xring[r*16 + gi*4 + ch] = x[r*4500 + b*12 + gi*3 + ch];
        }
    }
    ring[tid & 255] = 0.f;
    __syncthreads();

    if (wid == 0) {
        // ================= W0: snow recursion =================
        const float pTT     = -2.5f + params[(g*12+8)*16+m]*5.f;
        const float pCFMAX  =  0.5f + params[(g*12+9)*16+m]*9.5f;
        const float refCoef = (params[(g*12+10)*16+m]*0.1f)*pCFMAX;
        const float pCWH    =          params[(g*12+11)*16+m]*0.2f;
        const float negCMTT = -pCFMAX*pTT;
        const float refCTT  = refCoef*pTT;
        float SP = 0.001f, MW = 0.001f;
        for (int p = 0; p < NPHASE; ++p) {
            if (p < NCHUNK) {
                const float* xb = &xring[(p%3)*CH*16 + gl*4];
                float* rb = &rtbuf[(p&1)*CH*64 + lane];
                // ---- burst all 16 steps' inputs into registers ----
                float2 PT[CH];
                #pragma unroll
                for (int s = 0; s < CH; ++s)
                    PT[s] = *(const float2*)(xb + s*16);
                // ---- register-only chain ----
                #pragma unroll
                for (int s = 0; s < CH; ++s) {
                    const float Pm = PT[s].x, Tm = PT[s].y;
                    const float RAIN    = (Tm >= pTT) ? Pm : 0.f;
                    const float meltcap = fmaxf(fmaf(pCFMAX, Tm, negCMTT), 0.f);
                    const float refcap  = fmaxf(fmaf(-refCoef, Tm, refCTT), 0.f);
                    const float SP1 = SP + (Pm - RAIN);
                    const float melt = fminf(meltcap, SP1);
                    const float MW1 = MW + melt;
                    const float refreeze = fminf(refcap, MW1);
                    SP = SP1 - melt + refreeze;
                    const float MW2 = MW1 - refreeze;
                    const float tosoil = fmaxf(fmaf(-pCWH, SP, MW2), 0.f);
                    MW = MW2 - tosoil;
                    rb[s*64] = RAIN + tosoil;
                }
            }
            __syncthreads();
        }
    } else if (wid == 1) {
        // ================= W1: soil (SM) recursion =================
        const float bb  = 1.f  + params[(g*12+0)*16+m]*5.f;
        const float pFC = 50.f + params[(g*12+1)*16+m]*950.f;
        const float pLP = 0.2f + params[(g*12+5)*16+m]*0.8f;
        const float iLPFC = 1.f/(pLP*pFC);
        const float cc = -bb * flog2(pFC);       // sw = exp2(bb*log2(SM)+cc)
        float SM = 0.001f;
        for (int p = 0; p < NPHASE; ++p) {
            if (p >= 1 && p-1 < NCHUNK) {
                const int c = p-1;
                const float* xe = &xring[(c%3)*CH*16 + gl*4 + 2];
                const float* rb = &rtbuf[(c&1)*CH*64 + lane];
                float2* sb = &soilbuf[(c&1)*CH*64 + lane];
                // ---- burst inputs ----
                float rt[CH], Ev[CH];
                #pragma unroll
                for (int s = 0; s < CH; ++s) { rt[s] = rb[s*64]; Ev[s] = xe[s*16]; }
                // ---- register-only chain (exp2 fold, min3/max3 forms) ----
                #pragma unroll
                for (int s = 0; s < CH; ++s) {
                    const float sw  = fexp2(fmaf(bb, flog2(SM), cc));
                    const float SM1 = fmaf(-rt[s], sw, SM + rt[s]);
                    const float SM2 = fminf(SM1, pFC);
                    const float cE  = Ev[s] * iLPFC;
                    const float et  = fminf(fminf(SM2*cE, SM2), Ev[s]);  // v_min3
                    const float re  = fmaf(rt[s], sw, SM1 - SM2);
                    SM = fmaxf(fmaxf(fmaf(-SM2, cE, SM2), SM2 - Ev[s]), PRECS);
                    sb[s*64] = make_float2(re, et);
                }
            }
            __syncthreads();
        }
    } else if (wid == 2) {
        // ================= W2: response (SUZ,SLZ) recursion =================
        const float pK0   = 0.05f  + params[(g*12+2)*16+m]*0.85f;
        const float pK1   = 0.01f  + params[(g*12+3)*16+m]*0.49f;
        const float pK2   = 0.001f + params[(g*12+4)*16+m]*0.199f;
        const float pPERC =          params[(g*12+6)*16+m]*10.f;
        const float pUZL  =          params[(g*12+7)*16+m]*100.f;
        const float oneMinusK0 = 1.f - pK0, K0UZL = pK0*pUZL;
        float SUZ = 0.001f, SLZ = 0.001f;
        for (int p = 0; p < NPHASE; ++p) {
            if (p >= 2 && p-2 < NCHUNK) {
                const int c = p-2;
                const float2* sb = &soilbuf[(c&1)*CH*64 + lane];
                float* qb = &qbuf[(c&1)*CH*QROW + lane*4];
                // ---- burst inputs ----
                float2 rE[CH];
                #pragma unroll
                for (int s = 0; s < CH; ++s) rE[s] = sb[s*64];
                // ---- register-only chain ----
                #pragma unroll
                for (int s = 0; s < CH; ++s) {
                    const float SUZ1 = SUZ + rE[s].x;
                    const float SUZ2 = fmaxf(SUZ1 - pPERC, 0.f);
                    const float PERC = SUZ1 - SUZ2;
                    const float SUZ3 = fminf(SUZ2, fmaf(SUZ2, oneMinusK0, K0UZL));
                    const float Q0 = SUZ2 - SUZ3;
                    const float Q1 = pK1 * SUZ3;
                    SUZ = SUZ3 - Q1;
                    const float SLZ1 = SLZ + PERC;
                    const float Q2 = pK2 * SLZ1;
                    SLZ = SLZ1 - Q2;
                    *(float4*)(qb + s*QROW) = make_float4(Q0, Q1, Q2, rE[s].y);
                }
            }
            __syncthreads();
        }
    } else {
        // ================= W3: epilogue + x staging =================
        float wq[LENF];
        {
            const float ta  = rtwts[g*2+0] * 2.9f;
            const float tbv = rtwts[g*2+1] * 6.5f;
            const float aa = fmaxf(ta, 0.f) + 0.1f;
            const float th = fmaxf(tbv, 0.f) + 0.5f;
            const float c0v = expf(-lgammaf(aa)) * powf(th, -aa);
            float wsum = 0.f;
            #pragma unroll
            for (int k = 0; k < LENF; ++k) {
                const float tt = (float)k + 0.5f;
                wq[k] = c0v * powf(tt, aa-1.f) * expf(-tt/th);
                wsum += wq[k];
            }
            const float ws = inv16 / wsum;
            #pragma unroll
            for (int k = 0; k < LENF; ++k) wq[k] *= ws;
        }
        int rbase[3], bcol[3], lslot[3];
        #pragma unroll
        for (int j = 0; j < 3; ++j) {
            const int idx = lane + 64*j;
            const int r = idx/12, rem = idx - 12*r;
            const int gi = rem/3, ch = rem - 3*gi;
            rbase[j] = r;
            bcol[j]  = b*12 + gi*3 + ch;
            lslot[j] = r*16 + gi*4 + ch;
        }
        int st_o[5], st_g[5];
        #pragma unroll
        for (int j = 0; j < 5; ++j) {
            const int idx = lane + 64*j;
            const int tt = idx/20, cl = idx - 20*tt;
            st_o[j] = tt*OTW + cl;
            st_g[j] = tt*7500 + cl;
        }

        for (int p = 0; p < NPHASE; ++p) {
            // (a) issue next chunk's x loads early (hide HBM under epilogue)
            const bool do_stage = (p+1 < NCHUNK);
            float stg0=0.f, stg1=0.f, stg2=0.f;
            if (do_stage) {
                int r0 = (p+1)*CH + rbase[0]; r0 = (r0 < NSTEP) ? r0 : (NSTEP-1);
                int r1 = (p+1)*CH + rbase[1]; r1 = (r1 < NSTEP) ? r1 : (NSTEP-1);
                int r2 = (p+1)*CH + rbase[2]; r2 = (r2 < NSTEP) ? r2 : (NSTEP-1);
                stg0 = x[r0*4500 + bcol[0]];
                stg1 = x[r1*4500 + bcol[1]];
                stg2 = x[r2*4500 + bcol[2]];
            }
            // (b) epilogue for chunk q = p-3
            const int q = p - 3;
            if (q >= 0) {
                const int nstep = (q == NCHUNK-1) ? (NSTEP - (NCHUNK-1)*CH) : CH;
                const float* qb = &qbuf[(q&1)*CH*QROW];
                const int t = q*CH + m;
                float a0=0.f, a1=0.f, a2=0.f, a3=0.f;
                if (m < nstep) {
                    // ---- burst the 16 b128 reads, then tree-sum ----
                    float4 v[16];
                    #pragma unroll
                    for (int i = 0; i < 16; ++i)
                        v[i] = *(const float4*)&qb[m*QROW + gl*64 + i*4];
                    float4 s0 = v[0], s1 = v[1], s2 = v[2], s3 = v[3];
                    #pragma unroll
                    for (int i = 4; i < 16; i += 4) {
                        s0.x+=v[i].x;   s0.y+=v[i].y;   s0.z+=v[i].z;   s0.w+=v[i].w;
                        s1.x+=v[i+1].x; s1.y+=v[i+1].y; s1.z+=v[i+1].z; s1.w+=v[i+1].w;
                        s2.x+=v[i+2].x; s2.y+=v[i+2].y; s2.z+=v[i+2].z; s2.w+=v[i+2].w;
                        s3.x+=v[i+3].x; s3.y+=v[i+3].y; s3.z+=v[i+3].z; s3.w+=v[i+3].w;
                    }
                    a0 = (s0.x+s1.x) + (s2.x+s3.x);
                    a1 = (s0.y+s1.y) + (s2.y+s3.y);
                    a2 = (s0.z+s1.z) + (s2.z+s3.z);
                    a3 = (s0.w+s1.w) + (s2.w+s3.w);
                    ring[gl*64 + (t & 63)] = a0 + a1 + a2;
                }
                asm volatile("s_waitcnt lgkmcnt(0)" ::: "memory");
                if (m < nstep) {
                    // ---- burst conv ring reads, two-accumulator FMA ----
                    float rv[LENF];
                    #pragma unroll
                    for (int k = 0; k < LENF; ++k)
                        rv[k] = ring[gl*64 + ((t - k) & 63)];
                    float accA = 0.f, accB = 0.f;
                    #pragma unroll
                    for (int k = 0; k < LENF-1; k += 2) {
                        accA = fmaf(wq[k],   rv[k],   accA);
                        accB = fmaf(wq[k+1], rv[k+1], accB);
                    }
                    accA = fmaf(wq[LENF-1], rv[LENF-1], accA);
                    float* ot = &outtile[m*OTW + gl*5];
                    ot[0] = accA + accB;
                    ot[1] = a0*inv16; ot[2] = a1*inv16;
                    ot[3] = a2*inv16; ot[4] = a3*inv16;
                }
                asm volatile("s_waitcnt lgkmcnt(0)" ::: "memory");
                const int ndw = nstep*20;
                float* ob = out + q*CH*7500 + b*20;
                #pragma unroll
                for (int j = 0; j < 5; ++j) {
                    const int idx = lane + 64*j;
                    if (idx < ndw) ob[st_g[j]] = outtile[st_o[j]];
                }
            }
            // (c) commit staged x for chunk p+1 (visible after barrier)
            if (do_stage) {
                float* xd = &xring[((p+1)%3)*CH*16];
                xd[lslot[0]] = stg0; xd[lslot[1]] = stg1; xd[lslot[2]] = stg2;
            }
            __syncthreads();
        }
    }
}

extern "C" void kernel_launch(void* const* d_in, const int* in_sizes, int n_in,
                              void* d_out, int out_size, void* d_ws, size_t ws_size,
                              hipStream_t stream)
{
    const float* x      = (const float*)d_in[0];
    const float* params = (const float*)d_in[1];
    const float* rt     = (const float*)d_in[2];
    float* out = (float*)d_out;

    dim3 grid(NGRID / 4), block(256);
    hipLaunchKernelGGL(hbv_scan_kernel, grid, block, 0, stream, x, params, rt, out);
}